// Round 8
// baseline (153.917 us; speedup 1.0000x reference)
//
#include <hip/hip_runtime.h>

// Problem constants (hardcoded in reference)
constexpr int NB = 4096;   // batch
constexpr int ND = 32;     // feature dim
constexpr int ROWS = 128;  // T == S == 128
constexpr int SLICE_F4 = ROWS * ND / 4;   // 1024 float4 per (batch,tensor) slice
constexpr int BLOCKS = 2048;
constexpr int ITERS = (NB * 2) / BLOCKS;  // 4 slices per block

// Math identity: softmax over a trailing axis of size 1 == 1.0, so
//   out[b, 0:32]  = sum_s X1[b,s,:],   out[b, 32:64] = sum_t C[b,t,:]
// Pure streaming column-sum (~134 MB read, 1 MB write).
//
// History: R3 wave-per-batch 44us / R6 wave-per-(b,tensor) Occ 52% 43us /
// R7 forced-MLP (VGPR 36) 43us. All invariant at ~3.1 TB/s delivered read.
// Theory: 4096 waves streaming private 16KiB windows -> instantaneous
// request set scattered (1KiB pieces at 16KiB stride over 64MB) -> memory
// system serves ~3.1 TB/s (queueing-inflated latency). Copy-style kernels
// (m13 6.3 TB/s, RMSNorm 4.9 TB/s) sweep contiguously.
//
// This round: copy-style sweep. Block = 1024 thr = 16 waves reads EXACTLY
// one contiguous 16KiB slice per iteration (even blocks X1, odd blocks C);
// at any instant the 2048 blocks tile two contiguous 16MB regions.
// Reduction: 3x shfl_down within wave -> LDS[16][8] float4 -> 8 lanes sum
// 16 partials -> one float4 store each. 2-deep pipeline: next slice's load
// issues before this slice's barriers, so each wave always has a load in
// flight. No atomics; each output element written exactly once.

__device__ __forceinline__ float4 f4_add(float4 a, float4 b) {
    return make_float4(a.x + b.x, a.y + b.y, a.z + b.z, a.w + b.w);
}

__device__ __forceinline__ float4 f4_shfl_down(float4 v, int off) {
    return make_float4(__shfl_down(v.x, off, 64), __shfl_down(v.y, off, 64),
                       __shfl_down(v.z, off, 64), __shfl_down(v.w, off, 64));
}

__global__ __launch_bounds__(1024) void coatt_colsum(const float* __restrict__ C,
                                                     const float* __restrict__ X1,
                                                     float* __restrict__ out) {
    const int t    = threadIdx.x;     // 0..1023
    const int lane = t & 63;
    const int w    = t >> 6;          // wave 0..15
    const int isC  = blockIdx.x & 1;  // even blocks sum X1, odd blocks sum C
    const int bid2 = blockIdx.x >> 1; // 0..1023

    const float4* src = reinterpret_cast<const float4*>(isC ? C : X1);

    __shared__ float4 part[16][8];    // per-wave partials (2 KiB)

    // Software pipeline: load for slice k+1 is issued before slice k's
    // barriers, so each wave keeps a load in flight across the sync.
    float4 cur = src[(size_t)bid2 * SLICE_F4 + t];   // k = 0 (b = bid2)

    #pragma unroll
    for (int k = 0; k < ITERS; ++k) {
        const int b = bid2 + k * (BLOCKS / 2);
        float4 nxt = make_float4(0.f, 0.f, 0.f, 0.f);
        if (k + 1 < ITERS)
            nxt = src[((size_t)b + BLOCKS / 2) * SLICE_F4 + t];

        // Wave reduce over the 8 rows this wave holds (lane = row*8 + chunk;
        // strides 32/16/8 combine equal col-chunk = lane & 7).
        float4 s = cur;
        #pragma unroll
        for (int off = 32; off >= 8; off >>= 1)
            s = f4_add(s, f4_shfl_down(s, off));
        if (lane < 8) part[w][lane] = s;
        __syncthreads();

        if (t < 8) {
            float4 acc = part[0][t];
            #pragma unroll
            for (int ww = 1; ww < 16; ++ww)
                acc = f4_add(acc, part[ww][t]);
            // out[b, isC*32 + 4t .. 4t+3]
            reinterpret_cast<float4*>(out + (size_t)b * 64 + isC * 32)[t] = acc;
        }
        __syncthreads();   // protect LDS reuse next iteration
        cur = nxt;
    }
}

extern "C" void kernel_launch(void* const* d_in, const int* in_sizes, int n_in,
                              void* d_out, int out_size, void* d_ws, size_t ws_size,
                              hipStream_t stream) {
    // setup_inputs order: C, X1, W, Ws, Wc, was, wac
    const float* C  = (const float*)d_in[0];
    const float* X1 = (const float*)d_in[1];
    float* out = (float*)d_out;   // (B,1,64) fp32

    coatt_colsum<<<BLOCKS, 1024, 0, stream>>>(C, X1, out);
}